// Round 1
// baseline (270.597 us; speedup 1.0000x reference)
//
#include <hip/hip_runtime.h>

// SpatialTransform: out[c,z,y,x] = trilinear_sample(x[c], pos=(w,h,d) + flow - 0.5)
// Key identity: normalize->denormalize in the reference cancels to
//   ix = grid_x + flow_x - 0.5, and grid at (d,h,w) == (w,h,d) exactly.
// So sample_grid (d_in[2]) is never read: saves 49 MB of HBM traffic.

constexpr int Dd = 160, Hh = 160, Ww = 160;
constexpr int V = Dd * Hh * Ww;   // 4,096,000 voxels
constexpr int C = 2;

__global__ __launch_bounds__(256) void st_kernel(
    const float* __restrict__ x,
    const float* __restrict__ flow,
    float* __restrict__ out)
{
    int idx = blockIdx.x * 256 + threadIdx.x;
    if (idx >= V) return;

    int w = idx % Ww;
    int t = idx / Ww;
    int h = t % Hh;
    int d = t / Hh;

    // flow is (D,H,W,3) contiguous: 3 scalar loads, wave touches contiguous 768B
    float gx = (float)w + flow[3 * idx + 0] - 0.5f;
    float gy = (float)h + flow[3 * idx + 1] - 0.5f;
    float gz = (float)d + flow[3 * idx + 2] - 0.5f;

    float fx0 = floorf(gx), fy0 = floorf(gy), fz0 = floorf(gz);
    float fx = gx - fx0, fy = gy - fy0, fz = gz - fz0;
    int ix0 = (int)fx0, iy0 = (int)fy0, iz0 = (int)fz0;
    int ix1 = ix0 + 1, iy1 = iy0 + 1, iz1 = iz0 + 1;

    // fold per-axis validity (zero-padding) into per-axis weights:
    // product of axis weights*valids == corner weight * corner valid
    float wx0 = (ix0 >= 0 && ix0 < Ww) ? (1.0f - fx) : 0.0f;
    float wx1 = (ix1 >= 0 && ix1 < Ww) ? fx : 0.0f;
    float wy0 = (iy0 >= 0 && iy0 < Hh) ? (1.0f - fy) : 0.0f;
    float wy1 = (iy1 >= 0 && iy1 < Hh) ? fy : 0.0f;
    float wz0 = (iz0 >= 0 && iz0 < Dd) ? (1.0f - fz) : 0.0f;
    float wz1 = (iz1 >= 0 && iz1 < Dd) ? fz : 0.0f;

    int cx0 = min(max(ix0, 0), Ww - 1), cx1 = min(max(ix1, 0), Ww - 1);
    int cy0 = min(max(iy0, 0), Hh - 1), cy1 = min(max(iy1, 0), Hh - 1);
    int cz0 = min(max(iz0, 0), Dd - 1), cz1 = min(max(iz1, 0), Dd - 1);

    int r00 = (cz0 * Hh + cy0) * Ww;
    int r01 = (cz0 * Hh + cy1) * Ww;
    int r10 = (cz1 * Hh + cy0) * Ww;
    int r11 = (cz1 * Hh + cy1) * Ww;

    float wz0y0 = wz0 * wy0, wz0y1 = wz0 * wy1;
    float wz1y0 = wz1 * wy0, wz1y1 = wz1 * wy1;

#pragma unroll
    for (int c = 0; c < C; ++c) {
        const float* __restrict__ xc = x + c * V;
        float v000 = xc[r00 + cx0], v001 = xc[r00 + cx1];
        float v010 = xc[r01 + cx0], v011 = xc[r01 + cx1];
        float v100 = xc[r10 + cx0], v101 = xc[r10 + cx1];
        float v110 = xc[r11 + cx0], v111 = xc[r11 + cx1];
        float res = wz0y0 * (wx0 * v000 + wx1 * v001)
                  + wz0y1 * (wx0 * v010 + wx1 * v011)
                  + wz1y0 * (wx0 * v100 + wx1 * v101)
                  + wz1y1 * (wx0 * v110 + wx1 * v111);
        out[c * V + idx] = res;
    }
}

extern "C" void kernel_launch(void* const* d_in, const int* in_sizes, int n_in,
                              void* d_out, int out_size, void* d_ws, size_t ws_size,
                              hipStream_t stream) {
    const float* x    = (const float*)d_in[0];
    const float* flow = (const float*)d_in[1];
    // d_in[2] (sample_grid) intentionally unread: it is the identity meshgrid.
    float* out = (float*)d_out;
    int blocks = (V + 255) / 256;  // 16000 blocks of 256
    st_kernel<<<blocks, 256, 0, stream>>>(x, flow, out);
}

// Round 2
// 256.256 us; speedup vs baseline: 1.0560x; 1.0560x over previous
//
#include <hip/hip_runtime.h>

// SpatialTransform trilinear gather, transaction-count-optimized.
// Identity: ix = w + flow_x - 0.5 (normalize/denormalize cancels); sample_grid unread.
// Limiter (R1 rocprof): lane-address throughput (~1 addr/cyc/CU), not HBM BW.
// So: 4 voxels/thread (float4 flow loads), float2 paired x-gathers (8 instead of
// 16 per voxel), float4 NT stores. 21 -> 9.25 lane-addresses per voxel.

constexpr int Dd = 160, Hh = 160, Ww = 160;
constexpr int V  = Dd * Hh * Ww;       // 4,096,000
constexpr int NT = V / 4;              // 1,024,000 threads, 4 voxels each

typedef float v4f __attribute__((ext_vector_type(4)));
typedef float v2f __attribute__((ext_vector_type(2)));
typedef v2f uv2f __attribute__((aligned(4)));   // 4B-aligned float2 (gather pairs)

__global__ __launch_bounds__(256) void st_kernel(
    const float* __restrict__ x,
    const float* __restrict__ flow,
    float* __restrict__ out)
{
    int t = blockIdx.x * 256 + threadIdx.x;      // grid sized exactly: no bounds check
    int vbase = t * 4;                            // 160 % 4 == 0 -> 4 voxels share (h,d)
    int w0  = vbase % Ww;
    int tmp = vbase / Ww;
    int h   = tmp % Hh;
    int d   = tmp / Hh;

    // 12 contiguous floats of flow (3 per voxel), 16B aligned (48B * t)
    const v4f* fp = (const v4f*)(flow + 3 * vbase);
    v4f f0 = __builtin_nontemporal_load(fp);
    v4f f1 = __builtin_nontemporal_load(fp + 1);
    v4f f2 = __builtin_nontemporal_load(fp + 2);
    float fxv[4] = {f0.x, f0.w, f1.z, f2.y};
    float fyv[4] = {f0.y, f1.x, f1.w, f2.z};
    float fzv[4] = {f0.z, f1.y, f2.x, f2.w};

    float res0[4], res1[4];

#pragma unroll
    for (int j = 0; j < 4; ++j) {
        float gx = (float)(w0 + j) + fxv[j] - 0.5f;
        float gy = (float)h        + fyv[j] - 0.5f;
        float gz = (float)d        + fzv[j] - 0.5f;

        float fx0f = floorf(gx), fy0f = floorf(gy), fz0f = floorf(gz);
        float fx = gx - fx0f, fy = gy - fy0f, fz = gz - fz0f;
        int ix0 = (int)fx0f, iy0 = (int)fy0f, iz0 = (int)fz0f;

        // per-axis validity folded into weights (zero padding)
        float wx0 = (ix0 >= 0     && ix0 < Ww)     ? (1.0f - fx) : 0.0f;
        float wx1 = (ix0 + 1 >= 0 && ix0 + 1 < Ww) ? fx          : 0.0f;
        float wy0 = (iy0 >= 0     && iy0 < Hh)     ? (1.0f - fy) : 0.0f;
        float wy1 = (iy0 + 1 >= 0 && iy0 + 1 < Hh) ? fy          : 0.0f;
        float wz0 = (iz0 >= 0     && iz0 < Dd)     ? (1.0f - fz) : 0.0f;
        float wz1 = (iz0 + 1 >= 0 && iz0 + 1 < Dd) ? fz          : 0.0f;

        // float2 gather base along x; remap weights for the two clamp cases so
        // val_x = b0*u0 + b1*u1 holds for ALL ix0 (u = x[bx], x[bx+1]).
        int bx = min(max(ix0, 0), Ww - 2);
        float b0 = (ix0 == -1)     ? fx          : ((ix0 == Ww - 1) ? 0.0f : wx0);
        float b1 = (ix0 == Ww - 1) ? (1.0f - fx) : ((ix0 == -1)     ? 0.0f : wx1);

        int cy0 = min(max(iy0, 0), Hh - 1), cy1 = min(max(iy0 + 1, 0), Hh - 1);
        int cz0 = min(max(iz0, 0), Dd - 1), cz1 = min(max(iz0 + 1, 0), Dd - 1);

        int r00 = (cz0 * Hh + cy0) * Ww + bx;
        int r01 = (cz0 * Hh + cy1) * Ww + bx;
        int r10 = (cz1 * Hh + cy0) * Ww + bx;
        int r11 = (cz1 * Hh + cy1) * Ww + bx;

        float wz0y0 = wz0 * wy0, wz0y1 = wz0 * wy1;
        float wz1y0 = wz1 * wy0, wz1y1 = wz1 * wy1;

        // channel 0
        {
            uv2f p00 = *(const uv2f*)(x + r00);
            uv2f p01 = *(const uv2f*)(x + r01);
            uv2f p10 = *(const uv2f*)(x + r10);
            uv2f p11 = *(const uv2f*)(x + r11);
            res0[j] = wz0y0 * (b0 * p00.x + b1 * p00.y)
                    + wz0y1 * (b0 * p01.x + b1 * p01.y)
                    + wz1y0 * (b0 * p10.x + b1 * p10.y)
                    + wz1y1 * (b0 * p11.x + b1 * p11.y);
        }
        // channel 1
        {
            const float* xc = x + V;
            uv2f p00 = *(const uv2f*)(xc + r00);
            uv2f p01 = *(const uv2f*)(xc + r01);
            uv2f p10 = *(const uv2f*)(xc + r10);
            uv2f p11 = *(const uv2f*)(xc + r11);
            res1[j] = wz0y0 * (b0 * p00.x + b1 * p00.y)
                    + wz0y1 * (b0 * p01.x + b1 * p01.y)
                    + wz1y0 * (b0 * p10.x + b1 * p10.y)
                    + wz1y1 * (b0 * p11.x + b1 * p11.y);
        }
    }

    v4f o0 = {res0[0], res0[1], res0[2], res0[3]};
    v4f o1 = {res1[0], res1[1], res1[2], res1[3]};
    __builtin_nontemporal_store(o0, (v4f*)(out + vbase));        // 16B aligned
    __builtin_nontemporal_store(o1, (v4f*)(out + V + vbase));
}

extern "C" void kernel_launch(void* const* d_in, const int* in_sizes, int n_in,
                              void* d_out, int out_size, void* d_ws, size_t ws_size,
                              hipStream_t stream) {
    const float* x    = (const float*)d_in[0];
    const float* flow = (const float*)d_in[1];
    // d_in[2] (sample_grid) is the identity meshgrid: never read.
    float* out = (float*)d_out;
    st_kernel<<<NT / 256, 256, 0, stream>>>(x, flow, out);  // 4000 blocks
}